// Round 8
// baseline (133.188 us; speedup 1.0000x reference)
//
#include <hip/hip_runtime.h>

// Problem constants
#define BB 256
#define PP 128
#define KK 16
#define HH 128
#define OO 256
#define EE 18      // 2*(C+F)
#define XCH 10     // C + F + 1 (coords, feats, mask)
#define BIGD 1000000000.0f
#define GPT 8      // points per WG (4 waves x 2 points/wave)
#define NBLK ((BB * PP) / GPT)  // 4096

typedef __bf16 bf16x8 __attribute__((ext_vector_type(8)));
typedef __bf16 bf16x4 __attribute__((ext_vector_type(4)));
typedef float  f32x4  __attribute__((ext_vector_type(4)));
typedef unsigned long long ull;

__device__ __forceinline__ ull shfl_xor64(ull v, int m) {
    const int lo = __shfl_xor((int)(unsigned)v, m, 64);
    const int hi = __shfl_xor((int)(unsigned)(v >> 32), m, 64);
    return ((ull)(unsigned)hi << 32) | (unsigned)lo;
}

// ---------------------------------------------------------------------------
// Kernel 1: pack W2 and W1 into bf16 MFMA fragment order.
// W2p (B-frag, 16x16x32): [ct 16][ks 4][lane 64][j 8], elem = W2[ks*32+(l>>4)*8+j][ct*16+(l&15)]
// W1p (A-frag for h1^T = W1^T @ edge^T): [nt 8][lane 64][j 8],
//   elem = W1[k][nt*16+(l&15)] for k=(l>>4)*8+j < 18, else 0 (K padded to 32).
// ---------------------------------------------------------------------------
__global__ __launch_bounds__(256) void pack_w_kernel(const float* __restrict__ W1,
                                                     const float* __restrict__ W2,
                                                     __bf16* __restrict__ W2p,
                                                     __bf16* __restrict__ W1p) {
    const int t = blockIdx.x * 256 + threadIdx.x;  // 0 .. 36863
    if (t < 32768) {
        const int j  = t & 7;
        const int l  = (t >> 3) & 63;
        const int ks = (t >> 9) & 3;
        const int ct = t >> 11;
        const int row = ks * 32 + ((l >> 4) * 8) + j;
        const int col = ct * 16 + (l & 15);
        W2p[t] = (__bf16)W2[row * OO + col];
    } else {
        const int t2 = t - 32768;  // 0 .. 4095
        const int j  = t2 & 7;
        const int l  = (t2 >> 3) & 63;
        const int nt = t2 >> 9;
        const int k  = ((l >> 4) * 8) + j;
        const int n  = nt * 16 + (l & 15);
        W1p[t2] = (k < EE) ? (__bf16)W1[k * HH + n] : (__bf16)0.0f;
    }
}

// ---------------------------------------------------------------------------
// Kernel 2: fully-fused EdgeConv: per-block KNN + edge-MLP (all-MFMA).
//
// BITONIC-SELECT revision (resubmit of r7 after infra failure; audited:
// no OOB, no data-dependent loops, block-uniform barrier path).
// Model from r1-r6: duration = sum(per-wave serial latency) / (residency
// ~7 waves/CU x 256) -- residency never moves, so the lever is per-wave
// latency. r6 localized it to the radix-4 select (serial ballot->popc->
// SALU64->branch chain, ~15 latency round-trips/select).
// Replacement: branch-free wave-bitonic top-16 over the 128 keys, 2/lane,
// element index e=(lane<<1)|slot (slot exchanges are FREE in-lane):
//   - sort 8 ascending runs of 16: 10 layers, only 6 shuffled;
//   - 3 merge-prune rounds: keep-low-16 = min(A[p], B[15-p]) via
//     shfl_xor(15/23/39), + 4-layer bitonic resort (skipped on last --
//     only the winner SET matters, outputs are K-sums);
//   - winners end replicated in lanes 0..7 (2/lane); jn extracted by one
//     packed 16-bit shuffle. sknn LDS array + act-guard branches DELETED.
// key = (d_bits<<7)|j : unique, ascending == lexicographic (d,j) ==
// jax.lax.top_k stable order (d>=0 -> fp32 bits monotone as uint). Self is
// the unique d=0 min == the dropped "nearest": excluded upfront via BIGD
// (lengths>=18 so BIGD rows never reach top-16). dist2 via __fmul_rn/
// __fadd_rn matches numpy bit-exact. Winner->slot order is a permutation
// of the same winner set as r1-r6 (K-sum invariant).
// ---------------------------------------------------------------------------
__global__ __launch_bounds__(256, 4) void mlp_kernel(const float* __restrict__ x,
                                                     const __bf16* __restrict__ W1p,
                                                     const float* __restrict__ b1,
                                                     const __bf16* __restrict__ W2p,
                                                     const float* __restrict__ b2,
                                                     float* __restrict__ out) {
    __shared__ __bf16 sh1A[4 * GPT * 64 * 8];  // [ks4][g8][lane][j], 32 KB

    const int tid = threadIdx.x;
    const int lane = tid & 63;
    const int w = tid >> 6;          // 0..3
    const int quad = lane >> 4;
    const int lcol = lane & 15;

    const int pbase = blockIdx.x * GPT;
    const int bidx = pbase >> 7;
    const int i0 = pbase & (PP - 1);           // 16 WGs per batch item
    const float* xb = x + (size_t)bidx * PP * XCH;
    float* outrow = out + (size_t)pbase * (OO + 1);

    // all-8 masks (same values in every wave -> block-uniform predicate)
    const float mph = xb[(i0 + (lane & 7)) * XCH + (XCH - 1)];
    if (__all(mph == 0.0f)) {
        // out is re-poisoned before every launch: must write zeros
        for (int o = tid; o < GPT * (OO + 1); o += 256) outrow[o] = 0.0f;
        return;  // block-uniform: no barrier mismatch
    }

    // ---- candidate rows: loaded once, shared by this wave's 2 selects ----
    const int j0 = lane, j1 = lane + 64;
    const float2 c0 = *(const float2*)(xb + j0 * XCH);
    const float  m0 = xb[j0 * XCH + (XCH - 1)];
    const float2 c1 = *(const float2*)(xb + j1 * XCH);
    const float  m1 = xb[j1 * XCH + (XCH - 1)];

    // ---- this wave's 2 points ----
    const int iA = i0 + w * 2, iB = i0 + w * 2 + 1;
    const float2 ccA = *(const float2*)(xb + iA * XCH);
    const float2 ccB = *(const float2*)(xb + iB * XCH);

    // ---- GEMM1 A-fragments (issued now; consumed after the selects) ----
    bf16x8 wf[8];
#pragma unroll
    for (int nt = 0; nt < 8; ++nt)
        wf[nt] = *(const bf16x8*)&W1p[(size_t)((nt * 64 + lane) * 8)];

    // ================= KNN: 2 bitonic top-16 selects, interleaved ==========
    ull k0[2], k1[2];
    {
        float dx, dy, d;
        dx = ccA.x - c0.x; dy = ccA.y - c0.y;
        d = __fadd_rn(__fmul_rn(dx, dx), __fmul_rn(dy, dy));
        if (m0 <= 0.0f || j0 == iA) d = BIGD;
        k0[0] = ((ull)__float_as_uint(d) << 7) | (unsigned)j0;
        dx = ccA.x - c1.x; dy = ccA.y - c1.y;
        d = __fadd_rn(__fmul_rn(dx, dx), __fmul_rn(dy, dy));
        if (m1 <= 0.0f || j1 == iA) d = BIGD;
        k1[0] = ((ull)__float_as_uint(d) << 7) | (unsigned)j1;
        dx = ccB.x - c0.x; dy = ccB.y - c0.y;
        d = __fadd_rn(__fmul_rn(dx, dx), __fmul_rn(dy, dy));
        if (m0 <= 0.0f || j0 == iB) d = BIGD;
        k0[1] = ((ull)__float_as_uint(d) << 7) | (unsigned)j0;
        dx = ccB.x - c1.x; dy = ccB.y - c1.y;
        d = __fadd_rn(__fmul_rn(dx, dx), __fmul_rn(dy, dy));
        if (m1 <= 0.0f || j1 == iB) d = BIGD;
        k1[1] = ((ull)__float_as_uint(d) << 7) | (unsigned)j1;
    }

    // compare-exchange, partner at lane^sm (same slot). up-block mask upm
    // (0 = always ascending); I'm the lower index iff (lane&sm)==0.
    auto ce_x = [&](ull &k, int sm, int upm) {
        const ull pk = shfl_xor64(k, sm);
        const bool wmin = (((upm == 0) || ((lane & upm) == 0)) == ((lane & sm) == 0));
        const ull mn = (k < pk) ? k : pk;
        const ull mx = (k < pk) ? pk : k;
        k = wmin ? mn : mx;
    };
    // compare-exchange between slot0/slot1 in-lane (k0 is the lower index).
    auto ce_s = [&](ull &a, ull &b, int upm) {
        const bool up = (upm == 0) || ((lane & upm) == 0);
        const ull mn = (a < b) ? a : b;
        const ull mx = (a < b) ? b : a;
        a = up ? mn : mx;
        b = up ? mx : mn;
    };

    // phase 1: bitonic sort of each 16-run (pos p = ((lane&7)<<1)|slot).
    // layers (k,m): (2,1)(4,2)(4,1)(8,4)(8,2)(8,1)(16,8)(16,4)(16,2)(16,1)
#pragma unroll
    for (int pt = 0; pt < 2; ++pt) ce_s(k0[pt], k1[pt], 1);
#pragma unroll
    for (int pt = 0; pt < 2; ++pt) { ce_x(k0[pt], 1, 2); ce_x(k1[pt], 1, 2); }
#pragma unroll
    for (int pt = 0; pt < 2; ++pt) ce_s(k0[pt], k1[pt], 2);
#pragma unroll
    for (int pt = 0; pt < 2; ++pt) { ce_x(k0[pt], 2, 4); ce_x(k1[pt], 2, 4); }
#pragma unroll
    for (int pt = 0; pt < 2; ++pt) { ce_x(k0[pt], 1, 4); ce_x(k1[pt], 1, 4); }
#pragma unroll
    for (int pt = 0; pt < 2; ++pt) ce_s(k0[pt], k1[pt], 4);
#pragma unroll
    for (int pt = 0; pt < 2; ++pt) { ce_x(k0[pt], 4, 0); ce_x(k1[pt], 4, 0); }
#pragma unroll
    for (int pt = 0; pt < 2; ++pt) { ce_x(k0[pt], 2, 0); ce_x(k1[pt], 2, 0); }
#pragma unroll
    for (int pt = 0; pt < 2; ++pt) { ce_x(k0[pt], 1, 0); ce_x(k1[pt], 1, 0); }
#pragma unroll
    for (int pt = 0; pt < 2; ++pt) ce_s(k0[pt], k1[pt], 0);

    // merge-prune: keep lowest 16 of two sorted 16-runs whose groups differ
    // by revm's lane bit; rev pos = flip slot + lane bits 0-2 (+group bit).
    // Slot flip is realized by the a/b cross: a'=min(a,rb), b'=min(b,ra).
    auto merge_lo = [&](ull &a, ull &b, int revm, bool resort) {
        const ull ra = shfl_xor64(a, revm);
        const ull rb = shfl_xor64(b, revm);
        const ull na = (a < rb) ? a : rb;
        const ull nb = (b < ra) ? b : ra;
        a = na; b = nb;
        if (resort) {   // bitonic -> ascending: (16,8)(16,4)(16,2)(16,1)
            ce_x(a, 4, 0); ce_x(b, 4, 0);
            ce_x(a, 2, 0); ce_x(b, 2, 0);
            ce_x(a, 1, 0); ce_x(b, 1, 0);
            ce_s(a, b, 0);
        }
    };
#pragma unroll
    for (int pt = 0; pt < 2; ++pt) merge_lo(k0[pt], k1[pt], 15, true);   // lane bit3
#pragma unroll
    for (int pt = 0; pt < 2; ++pt) merge_lo(k0[pt], k1[pt], 23, true);   // lane bit4
#pragma unroll
    for (int pt = 0; pt < 2; ++pt) merge_lo(k0[pt], k1[pt], 39, false);  // lane bit5, set only

    // extraction: winner set occupies lanes 0..7 x 2 slots (replicated in
    // every 8-lane group). every lane needs winner[lcol]; pack both slots'
    // j into 16 bits, 1 shfl; lcol&1 == lane&1 selects the slot.
    const int srcl = (lane & 15) >> 1;
    const unsigned pkA = (unsigned)(k0[0] & 127) | ((unsigned)(k1[0] & 127) << 8);
    const unsigned pkB = (unsigned)(k0[1] & 127) | ((unsigned)(k1[1] & 127) << 8);
    const unsigned gA = (unsigned)__shfl((int)pkA, srcl, 64);
    const unsigned gB = (unsigned)__shfl((int)pkB, srcl, 64);
    int jn2[2];
    jn2[0] = (int)(((lane & 1) ? (gA >> 8) : gA) & 127u);
    jn2[1] = (int)(((lane & 1) ? (gB >> 8) : gB) & 127u);
    // masked points: keys are BIGD-ranked but low bits are still valid j in
    // [0,128) -> gather stays in-bounds; output row is zeroed by mask later.

    // ============ edge build + GEMM1 + epilogue-1, for both points ==========
    const f32x4 z4 = {0.0f, 0.0f, 0.0f, 0.0f};
#pragma unroll
    for (int p = 0; p < 2; ++p) {
        const int g = w * 2 + p;
        const int ip = i0 + g;
        const int jn = jn2[p];
        const float* ciP = xb + ip * XCH;   // wave-uniform (L1-hot)
        const float* cjP = xb + jn * XCH;
        const float2 a01 = *(const float2*)(ciP + 0);
        const float2 a23 = *(const float2*)(ciP + 2);
        const float2 a45 = *(const float2*)(ciP + 4);
        const float2 a67 = *(const float2*)(ciP + 6);
        const float  a8  = ciP[8];
        const float2 n01 = *(const float2*)(cjP + 0);
        const float2 n23 = *(const float2*)(cjP + 2);
        const float2 n45 = *(const float2*)(cjP + 4);
        const float2 n67 = *(const float2*)(cjP + 6);
        const float  n8  = cjP[8];

        float v[8];
#pragma unroll
        for (int e = 0; e < 8; ++e) v[e] = 0.0f;
        if (quad == 0) {           // channels 0..7 = center ch 0..7
            v[0] = a01.x; v[1] = a01.y; v[2] = a23.x; v[3] = a23.y;
            v[4] = a45.x; v[5] = a45.y; v[6] = a67.x; v[7] = a67.y;
        } else if (quad == 1) {    // ch 8 = center ch8; 9..15 = diff 0..6
            v[0] = a8;
            v[1] = n01.x - a01.x; v[2] = n01.y - a01.y;
            v[3] = n23.x - a23.x; v[4] = n23.y - a23.y;
            v[5] = n45.x - a45.x; v[6] = n45.y - a45.y;
            v[7] = n67.x - a67.x;
        } else if (quad == 2) {    // ch 16 = diff ch7; ch 17 = diff ch8
            v[0] = n67.y - a67.y;
            v[1] = n8 - a8;
        }                          // quad 3: zero padding (K 18 -> 32)

        bf16x8 ef;
#pragma unroll
        for (int e = 0; e < 8; ++e) ef[e] = (__bf16)v[e];

        // GEMM1 (MFMA): h1^T tiles; A = wf, B = ef
        f32x4 hh[8];
#pragma unroll
        for (int nt = 0; nt < 8; ++nt)
            hh[nt] = __builtin_amdgcn_mfma_f32_16x16x32_bf16(wf[nt], ef, z4, 0, 0, 0);

        // epilogue 1: relu(+b1), bf16 write into GEMM2 A-frag order
#pragma unroll
        for (int nt = 0; nt < 8; ++nt) {
            const int ks = nt >> 1;
            const int lp = (((nt * 2 + (quad >> 1)) & 3) << 4) | lcol;
            const f32x4 b1v = *(const f32x4*)&b1[nt * 16 + quad * 4];
            bf16x4 hv;
#pragma unroll
            for (int r = 0; r < 4; ++r)
                hv[r] = (__bf16)fmaxf(hh[nt][r] + b1v[r], 0.0f);
            *(bf16x4*)&sh1A[((ks * GPT + g) * 64 + lp) * 8 + (quad & 1) * 4] = hv;
        }
    }
    __syncthreads();

    // ---- GEMM2 (MFMA): 8 points x 256 cols, wave w owns cols w*64.. -------
    // g-halves x ct-pairs: acc live-set 32 f32 regs per sub-block; B-frags
    // WG-shared (each read once per 8 points).
#pragma unroll
    for (int gg = 0; gg < 2; ++gg) {
#pragma unroll
        for (int ch = 0; ch < 2; ++ch) {
            f32x4 acc[4][2];
#pragma unroll
            for (int gi = 0; gi < 4; ++gi) { acc[gi][0] = z4; acc[gi][1] = z4; }

#pragma unroll
            for (int ks = 0; ks < 4; ++ks) {
                bf16x8 af[4], bfr[2];
#pragma unroll
                for (int gi = 0; gi < 4; ++gi)
                    af[gi] = *(const bf16x8*)&sh1A[((ks * GPT + gg * 4 + gi) * 64 + lane) * 8];
#pragma unroll
                for (int c = 0; c < 2; ++c)
                    bfr[c] = *(const bf16x8*)&W2p[(size_t)((((w * 4 + ch * 2 + c) * 4 + ks) * 64 + lane) * 8)];
#pragma unroll
                for (int gi = 0; gi < 4; ++gi)
#pragma unroll
                    for (int c = 0; c < 2; ++c)
                        acc[gi][c] = __builtin_amdgcn_mfma_f32_16x16x32_bf16(
                            af[gi], bfr[c], acc[gi][c], 0, 0, 0);
            }

            // epilogue 2: relu(+b2), K-sum = tile column sum via shuffles
            // tile gi's 16 rows = point (gg*4+gi)'s K neighbors. 4 rows
            // in-lane, fold quads (xor 16, 32); lane quad q keeps pt gg*4+q.
#pragma unroll
            for (int c = 0; c < 2; ++c) {
                const int col = w * 64 + (ch * 2 + c) * 16 + lcol;
                const float bc = b2[col];
                float val = 0.0f;
#pragma unroll
                for (int gi = 0; gi < 4; ++gi) {
                    float s = 0.0f;
#pragma unroll
                    for (int r = 0; r < 4; ++r) s += fmaxf(acc[gi][c][r] + bc, 0.0f);
                    s += __shfl_xor(s, 16, 64);
                    s += __shfl_xor(s, 32, 64);
                    if (quad == gi) val = s;   // lane (quad=gi,lcol) keeps
                }
                const float mp = xb[(i0 + gg * 4 + quad) * XCH + (XCH - 1)];
                outrow[(size_t)(gg * 4 + quad) * (OO + 1) + col] = val * (mp * (1.0f / KK));
            }
        }
    }
    if (tid < GPT)
        outrow[(size_t)tid * (OO + 1) + OO] = xb[(i0 + tid) * XCH + (XCH - 1)];
}

extern "C" void kernel_launch(void* const* d_in, const int* in_sizes, int n_in,
                              void* d_out, int out_size, void* d_ws, size_t ws_size,
                              hipStream_t stream) {
    const float* x  = (const float*)d_in[0];
    const float* W1 = (const float*)d_in[1];
    const float* b1 = (const float*)d_in[2];
    const float* W2 = (const float*)d_in[3];
    const float* b2 = (const float*)d_in[4];
    float* out = (float*)d_out;

    __bf16* W2p = (__bf16*)d_ws;                    // 64 KB
    __bf16* W1p = (__bf16*)((char*)d_ws + 65536);   // 8 KB

    pack_w_kernel<<<144, 256, 0, stream>>>(W1, W2, W2p, W1p);

    mlp_kernel<<<NBLK, 256, 0, stream>>>(x, W1p, b1, W2p, b2, out);
}

// Round 9
// 126.048 us; speedup vs baseline: 1.0566x; 1.0566x over previous
//
#include <hip/hip_runtime.h>

// Problem constants
#define BB 256
#define PP 128
#define KK 16
#define HH 128
#define OO 256
#define EE 18      // 2*(C+F)
#define XCH 10     // C + F + 1 (coords, feats, mask)
#define BIGD 1000000000.0f
#define GPT 8      // points per WG (4 waves x 2 points/wave)
#define NBLK ((BB * PP) / GPT)  // 4096

typedef __bf16 bf16x8 __attribute__((ext_vector_type(8)));
typedef __bf16 bf16x4 __attribute__((ext_vector_type(4)));
typedef float  f32x4  __attribute__((ext_vector_type(4)));
typedef unsigned long long ull;

// ---------------------------------------------------------------------------
// Kernel 1: pack W2 and W1 into bf16 MFMA fragment order.
// W2p (B-frag, 16x16x32): [ct 16][ks 4][lane 64][j 8], elem = W2[ks*32+(l>>4)*8+j][ct*16+(l&15)]
// W1p (A-frag for h1^T = W1^T @ edge^T): [nt 8][lane 64][j 8],
//   elem = W1[k][nt*16+(l&15)] for k=(l>>4)*8+j < 18, else 0 (K padded to 32).
// ---------------------------------------------------------------------------
__global__ __launch_bounds__(256) void pack_w_kernel(const float* __restrict__ W1,
                                                     const float* __restrict__ W2,
                                                     __bf16* __restrict__ W2p,
                                                     __bf16* __restrict__ W1p) {
    const int t = blockIdx.x * 256 + threadIdx.x;  // 0 .. 36863
    if (t < 32768) {
        const int j  = t & 7;
        const int l  = (t >> 3) & 63;
        const int ks = (t >> 9) & 3;
        const int ct = t >> 11;
        const int row = ks * 32 + ((l >> 4) * 8) + j;
        const int col = ct * 16 + (l & 15);
        W2p[t] = (__bf16)W2[row * OO + col];
    } else {
        const int t2 = t - 32768;  // 0 .. 4095
        const int j  = t2 & 7;
        const int l  = (t2 >> 3) & 63;
        const int nt = t2 >> 9;
        const int k  = ((l >> 4) * 8) + j;
        const int n  = nt * 16 + (l & 15);
        W1p[t2] = (k < EE) ? (__bf16)W1[k * HH + n] : (__bf16)0.0f;
    }
}

// ---------------------------------------------------------------------------
// Kernel 2: fully-fused EdgeConv: per-block KNN + edge-MLP (all-MFMA).
//
// LATENCY-CUT revision of the r6 radix structure (r8 bitonic refuted: DS
// shuffle chains are SLOWER than ballot rounds on CDNA). Per-wave serial
// stages removed:
//  - mask pre-load stage DELETED: validity bits come from ballots of the
//    candidate masks (loaded anyway); all-masked exit after candidate loads.
//  - centers via 4 shuffles from candidate regs (bit-identical, 2 loads cut).
//  - act / mscale / mask-channel synthesized from ballot bits (masks are
//    exact 0.0/1.0 floats by construction) -- ~10 loads/wave cut.
//  - center rows hoisted ABOVE the radix loop (hide under ballot chain).
//  - both points' gather loads issued before either GEMM1.
//  - GEMM2: bfr (W2p B-frags) hoisted across the gg loop: 32 -> 16 frag
//    reads/wave (halves W2p L1 traffic + exposed VMEM latency).
// KNN select: r6's radix-4 over key=(d_bits<<7)|j, 2 points batched through
// one round loop (ballots back-to-back), fast-exit at |A|==need. Ascending
// key order == jax.lax.top_k stable order; self excluded via BIGD; dist2
// via __fmul_rn/__fadd_rn matches numpy bit-exact. Winner SET == r1-r6.
// ---------------------------------------------------------------------------
__global__ __launch_bounds__(256, 4) void mlp_kernel(const float* __restrict__ x,
                                                     const __bf16* __restrict__ W1p,
                                                     const float* __restrict__ b1,
                                                     const __bf16* __restrict__ W2p,
                                                     const float* __restrict__ b2,
                                                     float* __restrict__ out) {
    __shared__ __bf16 sh1A[4 * GPT * 64 * 8];  // [ks4][g8][lane][j], 32 KB
    __shared__ int    sknn[GPT][KK];           // per-point winner slots

    const int tid = threadIdx.x;
    const int lane = tid & 63;
    const int w = tid >> 6;          // 0..3
    const int quad = lane >> 4;
    const int lcol = lane & 15;

    const int pbase = blockIdx.x * GPT;
    const int bidx = pbase >> 7;
    const int i0 = pbase & (PP - 1);           // 16 WGs per batch item
    const float* xb = x + (size_t)bidx * PP * XCH;
    float* outrow = out + (size_t)pbase * (OO + 1);

    // ---- candidate rows (these loads start the wave; nothing precedes) ----
    const int j0 = lane, j1 = lane + 64;
    const float2 c0 = *(const float2*)(xb + j0 * XCH);
    const float  m0 = xb[j0 * XCH + (XCH - 1)];
    const float2 c1 = *(const float2*)(xb + j1 * XCH);
    const float  m1 = xb[j1 * XCH + (XCH - 1)];

    // ---- GEMM1 A-fragments + center rows: issued early, consumed late ----
    bf16x8 wf[8];
#pragma unroll
    for (int nt = 0; nt < 8; ++nt)
        wf[nt] = *(const bf16x8*)&W1p[(size_t)((nt * 64 + lane) * 8)];

    const int iA = i0 + w * 2, iB = iA + 1;
    const float* ciA = xb + iA * XCH;   // wave-uniform
    const float* ciB = xb + iB * XCH;
    float2 arow01[2], arow23[2], arow45[2], arow67[2];
    float  arow8[2];
    arow01[0] = *(const float2*)(ciA + 0); arow23[0] = *(const float2*)(ciA + 2);
    arow45[0] = *(const float2*)(ciA + 4); arow67[0] = *(const float2*)(ciA + 6);
    arow8[0]  = ciA[8];
    arow01[1] = *(const float2*)(ciB + 0); arow23[1] = *(const float2*)(ciB + 2);
    arow45[1] = *(const float2*)(ciB + 4); arow67[1] = *(const float2*)(ciB + 6);
    arow8[1]  = ciB[8];

    // ---- validity bits from ballots (mask is exactly 0.0/1.0) ----
    const ull B0 = __ballot(m0 != 0.0f);   // rows 0..63
    const ull B1 = __ballot(m1 != 0.0f);   // rows 64..127
    const ull selB = (i0 & 64) ? B1 : B0;  // this WG's 8 rows are in one half
    const unsigned vbits = (unsigned)((selB >> (i0 & 63)) & 0xFFull);
    if (vbits == 0u) {
        // out is re-poisoned before every launch: must write zeros
        for (int o = tid; o < GPT * (OO + 1); o += 256) outrow[o] = 0.0f;
        return;  // wave/block-uniform: no barrier mismatch
    }

    // ---- centers via shuffle from candidate regs (bit-identical) ----
    const bool hiA = (iA & 64) != 0;       // iA,iB in the same half (i0%8==0)
    const float selx = hiA ? c1.x : c0.x;
    const float sely = hiA ? c1.y : c0.y;
    const float ccAx = __shfl(selx, iA & 63, 64);
    const float ccAy = __shfl(sely, iA & 63, 64);
    const float ccBx = __shfl(selx, iB & 63, 64);
    const float ccBy = __shfl(sely, iB & 63, 64);

    // ================= KNN: 2 radix-4 selects batched through one loop =====
    unsigned db0[2], db1[2];
    {
        float dx, dy, d;
        dx = ccAx - c0.x; dy = ccAy - c0.y;
        d = __fadd_rn(__fmul_rn(dx, dx), __fmul_rn(dy, dy));
        if (m0 <= 0.0f || j0 == iA) d = BIGD;
        db0[0] = __float_as_uint(d);
        dx = ccAx - c1.x; dy = ccAy - c1.y;
        d = __fadd_rn(__fmul_rn(dx, dx), __fmul_rn(dy, dy));
        if (m1 <= 0.0f || j1 == iA) d = BIGD;
        db1[0] = __float_as_uint(d);
        dx = ccBx - c0.x; dy = ccBy - c0.y;
        d = __fadd_rn(__fmul_rn(dx, dx), __fmul_rn(dy, dy));
        if (m0 <= 0.0f || j0 == iB) d = BIGD;
        db0[1] = __float_as_uint(d);
        dx = ccBx - c1.x; dy = ccBy - c1.y;
        d = __fadd_rn(__fmul_rn(dx, dx), __fmul_rn(dy, dy));
        if (m1 <= 0.0f || j1 == iB) d = BIGD;
        db1[1] = __float_as_uint(d);
    }

    ull A0[2], A1[2], W0[2], W1g[2];
    int need[2], asz[2];
#pragma unroll
    for (int p = 0; p < 2; ++p) {
        A0[p] = ~0ull; A1[p] = ~0ull; W0[p] = 0ull; W1g[p] = 0ull;
        need[p] = ((vbits >> (w * 2 + p)) & 1u) ? KK : 0;
        asz[p] = 128;
    }

    // phase A: radix-4 digits over d bits (30,29),(28,27),...,(2,1)
#pragma unroll 1
    for (int t = 14; t >= 0; --t) {
#pragma unroll
        for (int p = 0; p < 2; ++p) {
            if (need[p]) {   // wave-uniform guard
                const unsigned dg0 = (db0[p] >> (2 * t + 1)) & 3u;
                const unsigned dg1 = (db1[p] >> (2 * t + 1)) & 3u;
                const ull p0_0  = __ballot(dg0 == 0u);
                const ull p1_0  = __ballot(dg1 == 0u);
                const ull p0_01 = __ballot(dg0 <= 1u);
                const ull p1_01 = __ballot(dg1 <= 1u);
                const ull p0_02 = __ballot(dg0 <= 2u);
                const ull p1_02 = __ballot(dg1 <= 2u);
                const ull z0_0  = A0[p] & p0_0,  z1_0  = A1[p] & p1_0;
                const ull z0_01 = A0[p] & p0_01, z1_01 = A1[p] & p1_01;
                const ull z0_02 = A0[p] & p0_02, z1_02 = A1[p] & p1_02;
                const int c0c = __popcll(z0_0)  + __popcll(z1_0);
                const int c01 = __popcll(z0_01) + __popcll(z1_01);
                const int c02 = __popcll(z0_02) + __popcll(z1_02);
                if (c0c >= need[p]) {
                    A0[p] = z0_0; A1[p] = z1_0; asz[p] = c0c;
                } else if (c01 >= need[p]) {
                    W0[p] |= z0_0; W1g[p] |= z1_0; need[p] -= c0c;
                    A0[p] = z0_01 & ~p0_0; A1[p] = z1_01 & ~p1_0; asz[p] = c01 - c0c;
                } else if (c02 >= need[p]) {
                    W0[p] |= z0_01; W1g[p] |= z1_01; need[p] -= c01;
                    A0[p] = z0_02 & ~p0_01; A1[p] = z1_02 & ~p1_01; asz[p] = c02 - c01;
                } else {
                    W0[p] |= z0_02; W1g[p] |= z1_02; need[p] -= c02;
                    A0[p] &= ~p0_02; A1[p] &= ~p1_02; asz[p] -= c02;
                }
                if (asz[p] == need[p]) {
                    W0[p] |= A0[p]; W1g[p] |= A1[p];
                    A0[p] = A1[p] = 0ull; need[p] = 0;
                }
            }
        }
        if (!(need[0] | need[1])) break;
    }
    // phases A' (last d bit) + B (index bits 6..0), per point
#pragma unroll
    for (int p = 0; p < 2; ++p) {
        auto stepP = [&](ull q0, ull q1) {
            const ull z0 = A0[p] & q0;
            const ull z1 = A1[p] & q1;
            const int c = __popcll(z0) + __popcll(z1);
            if (c == need[p]) { W0[p] |= z0; W1g[p] |= z1; A0[p] = A1[p] = 0ull; need[p] = 0; }
            else if (c > need[p]) { A0[p] = z0; A1[p] = z1; asz[p] = c; }
            else { W0[p] |= z0; W1g[p] |= z1; need[p] -= c; A0[p] &= ~z0; A1[p] &= ~z1; asz[p] -= c; }
        };
        if (need[p]) {
            const ull q0 = __ballot((db0[p] & 1u) == 0u);
            const ull q1 = __ballot((db1[p] & 1u) == 0u);
            stepP(q0, q1);
        }
        if (need[p]) stepP(~0ull, 0ull);  // index bit 6: all j0=0, all j1=1
        {
            const ull M5 = 0x00000000FFFFFFFFull;
            const ull M4 = 0x0000FFFF0000FFFFull;
            const ull M3 = 0x00FF00FF00FF00FFull;
            const ull M2 = 0x0F0F0F0F0F0F0F0Full;
            const ull M1 = 0x3333333333333333ull;
            const ull M0 = 0x5555555555555555ull;
            if (need[p]) stepP(M5, M5);
            if (need[p]) stepP(M4, M4);
            if (need[p]) stepP(M3, M3);
            if (need[p]) stepP(M2, M2);
            if (need[p]) stepP(M1, M1);
            if (need[p]) stepP(M0, M0);
        }
        W0[p] |= A0[p]; W1g[p] |= A1[p];  // keys unique => remaining = rest

        const int g = w * 2 + p;
        if ((vbits >> g) & 1u) {
            unsigned int mb0 = __builtin_amdgcn_mbcnt_lo((unsigned)(W0[p] & 0xffffffffull), 0u);
            mb0 = __builtin_amdgcn_mbcnt_hi((unsigned)(W0[p] >> 32), mb0);
            unsigned int mb1 = __builtin_amdgcn_mbcnt_lo((unsigned)(W1g[p] & 0xffffffffull), 0u);
            mb1 = __builtin_amdgcn_mbcnt_hi((unsigned)(W1g[p] >> 32), mb1);
            const int base1 = __popcll(W0[p]);
            if ((W0[p] >> lane) & 1ull) sknn[g][mb0] = j0;
            if ((W1g[p] >> lane) & 1ull) sknn[g][base1 + mb1] = j1;
        } else {
            if (lane < KK) sknn[g][lane] = 0;  // dummy valid indices (masked)
        }
    }
    // NO barrier: wave reads only its own sknn rows (DS in-order per wave)

    // ============ gather both points' neighbor rows, then GEMM1 x2 =========
    const int jnA = sknn[w * 2 + 0][lcol];
    const int jnB = sknn[w * 2 + 1][lcol];
    float2 nrow01[2], nrow23[2], nrow45[2], nrow67[2];
    float  nrow8[2];
    {
        const float* cjA = xb + jnA * XCH;
        const float* cjB = xb + jnB * XCH;
        nrow01[0] = *(const float2*)(cjA + 0); nrow23[0] = *(const float2*)(cjA + 2);
        nrow45[0] = *(const float2*)(cjA + 4); nrow67[0] = *(const float2*)(cjA + 6);
        nrow8[0]  = cjA[8];
        nrow01[1] = *(const float2*)(cjB + 0); nrow23[1] = *(const float2*)(cjB + 2);
        nrow45[1] = *(const float2*)(cjB + 4); nrow67[1] = *(const float2*)(cjB + 6);
        nrow8[1]  = cjB[8];
    }

    const f32x4 z4 = {0.0f, 0.0f, 0.0f, 0.0f};
#pragma unroll
    for (int p = 0; p < 2; ++p) {
        const int g = w * 2 + p;
        const float2 a01 = arow01[p], a23 = arow23[p], a45 = arow45[p], a67 = arow67[p];
        const float  a8  = arow8[p];
        const float2 n01 = nrow01[p], n23 = nrow23[p], n45 = nrow45[p], n67 = nrow67[p];
        const float  n8  = nrow8[p];

        float v[8];
#pragma unroll
        for (int e = 0; e < 8; ++e) v[e] = 0.0f;
        if (quad == 0) {           // channels 0..7 = center ch 0..7
            v[0] = a01.x; v[1] = a01.y; v[2] = a23.x; v[3] = a23.y;
            v[4] = a45.x; v[5] = a45.y; v[6] = a67.x; v[7] = a67.y;
        } else if (quad == 1) {    // ch 8 = center ch8; 9..15 = diff 0..6
            v[0] = a8;
            v[1] = n01.x - a01.x; v[2] = n01.y - a01.y;
            v[3] = n23.x - a23.x; v[4] = n23.y - a23.y;
            v[5] = n45.x - a45.x; v[6] = n45.y - a45.y;
            v[7] = n67.x - a67.x;
        } else if (quad == 2) {    // ch 16 = diff ch7; ch 17 = diff ch8
            v[0] = n67.y - a67.y;
            v[1] = n8 - a8;
        }                          // quad 3: zero padding (K 18 -> 32)

        bf16x8 ef;
#pragma unroll
        for (int e = 0; e < 8; ++e) ef[e] = (__bf16)v[e];

        // GEMM1 (MFMA): h1^T tiles; A = wf, B = ef
        f32x4 hh[8];
#pragma unroll
        for (int nt = 0; nt < 8; ++nt)
            hh[nt] = __builtin_amdgcn_mfma_f32_16x16x32_bf16(wf[nt], ef, z4, 0, 0, 0);

        // epilogue 1: relu(+b1), bf16 write into GEMM2 A-frag order
#pragma unroll
        for (int nt = 0; nt < 8; ++nt) {
            const int ks = nt >> 1;
            const int lp = (((nt * 2 + (quad >> 1)) & 3) << 4) | lcol;
            const f32x4 b1v = *(const f32x4*)&b1[nt * 16 + quad * 4];
            bf16x4 hv;
#pragma unroll
            for (int r = 0; r < 4; ++r)
                hv[r] = (__bf16)fmaxf(hh[nt][r] + b1v[r], 0.0f);
            *(bf16x4*)&sh1A[((ks * GPT + g) * 64 + lp) * 8 + (quad & 1) * 4] = hv;
        }
    }
    __syncthreads();

    // ---- GEMM2 (MFMA): 8 points x 256 cols, wave w owns cols w*64.. -------
    // bfr hoisted across gg: W2p frag reads halved (16/wave). acc live-set
    // 32 f32 regs per gg sub-block; B-frags WG-shared.
#pragma unroll
    for (int ch = 0; ch < 2; ++ch) {
        bf16x8 bfr[4][2];
#pragma unroll
        for (int ks = 0; ks < 4; ++ks)
#pragma unroll
            for (int c = 0; c < 2; ++c)
                bfr[ks][c] = *(const bf16x8*)&W2p[(size_t)((((w * 4 + ch * 2 + c) * 4 + ks) * 64 + lane) * 8)];

#pragma unroll
        for (int gg = 0; gg < 2; ++gg) {
            f32x4 acc[4][2];
#pragma unroll
            for (int gi = 0; gi < 4; ++gi) { acc[gi][0] = z4; acc[gi][1] = z4; }

#pragma unroll
            for (int ks = 0; ks < 4; ++ks) {
                bf16x8 af[4];
#pragma unroll
                for (int gi = 0; gi < 4; ++gi)
                    af[gi] = *(const bf16x8*)&sh1A[((ks * GPT + gg * 4 + gi) * 64 + lane) * 8];
#pragma unroll
                for (int gi = 0; gi < 4; ++gi)
#pragma unroll
                    for (int c = 0; c < 2; ++c)
                        acc[gi][c] = __builtin_amdgcn_mfma_f32_16x16x32_bf16(
                            af[gi], bfr[ks][c], acc[gi][c], 0, 0, 0);
            }

            // epilogue 2: relu(+b2), K-sum = tile column sum via shuffles
            // tile gi's 16 rows = point (gg*4+gi)'s K neighbors. 4 rows
            // in-lane, fold quads (xor 16, 32); lane quad q keeps pt gg*4+q.
#pragma unroll
            for (int c = 0; c < 2; ++c) {
                const int col = w * 64 + (ch * 2 + c) * 16 + lcol;
                const float bc = b2[col];
                float val = 0.0f;
#pragma unroll
                for (int gi = 0; gi < 4; ++gi) {
                    float s = 0.0f;
#pragma unroll
                    for (int r = 0; r < 4; ++r) s += fmaxf(acc[gi][c][r] + bc, 0.0f);
                    s += __shfl_xor(s, 16, 64);
                    s += __shfl_xor(s, 32, 64);
                    if (quad == gi) val = s;   // lane (quad=gi,lcol) keeps
                }
                // mask of point gg*4+quad from validity bits (mask is 0/1)
                const float mscale =
                    ((vbits >> (gg * 4 + quad)) & 1u) ? (1.0f / KK) : 0.0f;
                outrow[(size_t)(gg * 4 + quad) * (OO + 1) + col] = val * mscale;
            }
        }
    }
    if (tid < GPT)
        outrow[(size_t)tid * (OO + 1) + OO] = ((vbits >> tid) & 1u) ? 1.0f : 0.0f;
}

extern "C" void kernel_launch(void* const* d_in, const int* in_sizes, int n_in,
                              void* d_out, int out_size, void* d_ws, size_t ws_size,
                              hipStream_t stream) {
    const float* x  = (const float*)d_in[0];
    const float* W1 = (const float*)d_in[1];
    const float* b1 = (const float*)d_in[2];
    const float* W2 = (const float*)d_in[3];
    const float* b2 = (const float*)d_in[4];
    float* out = (float*)d_out;

    __bf16* W2p = (__bf16*)d_ws;                    // 64 KB
    __bf16* W1p = (__bf16*)((char*)d_ws + 65536);   // 8 KB

    pack_w_kernel<<<144, 256, 0, stream>>>(W1, W2, W2p, W1p);

    mlp_kernel<<<NBLK, 256, 0, stream>>>(x, W1p, b1, W2p, b2, out);
}